// Round 1
// 3908.427 us; speedup vs baseline: 1.0404x; 1.0404x over previous
//
#include <hip/hip_runtime.h>

#define HDIM  1024
#define BDIM  64
#define TDIM  512
#define FRAGB 131072            // bytes per fragment-order activation matrix (64x1024 bf16)
#define FRAGE 65536             // elements per fragment matrix
#define WPAD  1048              // weight LDS row stride in bf16 (524 words, %32=12 -> spread)
#define SLOTS 4                 // o1 ring slots (small mode only)
#define NGRP  8                 // arrival sub-groups per layer (16 blocks each)

typedef __bf16 bf16x8 __attribute__((ext_vector_type(8)));
typedef float  f32x4  __attribute__((ext_vector_type(4)));
typedef int    i32x4  __attribute__((ext_vector_type(4)));

#define MFMA(a, b, c) __builtin_amdgcn_mfma_f32_16x16x32_bf16(a, b, c, 0, 0, 0)

// MALL-coherent 16B load (bypasses L1+L2) -- small mode only
#define GL(dst, p, off) \
    asm volatile("global_load_dwordx4 %0, %1, off offset:" off " sc0 sc1" \
                 : "=v"(dst) : "v"(p) : "memory")
#define GLF16(f, p) do { \
    const char* p0_ = (const char*)(p); \
    const char* p1_ = p0_ + 4096; const char* p2_ = p0_ + 8192; const char* p3_ = p0_ + 12288; \
    GL(f[0],  p0_, "0"); GL(f[1],  p0_, "1024"); GL(f[2],  p0_, "2048"); GL(f[3],  p0_, "3072"); \
    GL(f[4],  p1_, "0"); GL(f[5],  p1_, "1024"); GL(f[6],  p1_, "2048"); GL(f[7],  p1_, "3072"); \
    GL(f[8],  p2_, "0"); GL(f[9],  p2_, "1024"); GL(f[10], p2_, "2048"); GL(f[11], p2_, "3072"); \
    GL(f[12], p3_, "0"); GL(f[13], p3_, "1024"); GL(f[14], p3_, "2048"); GL(f[15], p3_, "3072"); \
} while (0)
#define WAITV() asm volatile("s_waitcnt vmcnt(0)" ::: "memory")
#define GS16(p, v) \
    asm volatile("global_store_dwordx4 %0, %1, off sc0 sc1" :: "v"(p), "v"(v) : "memory")

__device__ __forceinline__ float sigf(float x) { return 1.0f / (1.0f + expf(-x)); }

__device__ __forceinline__ bf16x8 cvt8(const float* p) {
    const f32x4* q = (const f32x4*)p;
    f32x4 a = q[0], b = q[1];
    bf16x8 r;
    r[0] = (__bf16)a[0]; r[1] = (__bf16)a[1]; r[2] = (__bf16)a[2]; r[3] = (__bf16)a[3];
    r[4] = (__bf16)b[0]; r[5] = (__bf16)b[1]; r[6] = (__bf16)b[2]; r[7] = (__bf16)b[3];
    return r;
}

// ---- wave-local spin on 8 sub-counters (16-way fan-in each); no block barrier ----
__device__ __forceinline__ void wspin(const int* base) {
    int l = threadIdx.x & 63;
    const int* p = (l < 8) ? base + l * 16 : nullptr;
    for (;;) {
        int v = p ? __hip_atomic_load(p, __ATOMIC_RELAXED, __HIP_MEMORY_SCOPE_AGENT) : 16;
        if (__all(v >= 16)) break;
        __builtin_amdgcn_s_sleep(1);
    }
}
__device__ __forceinline__ void spin1(const int* c, int n) {
    if (threadIdx.x == 0)
        while (__hip_atomic_load(c, __ATOMIC_RELAXED, __HIP_MEMORY_SCOPE_AGENT) < n)
            __builtin_amdgcn_s_sleep(1);
    __syncthreads();
}

// streaming GEMM slice: 2 batch tiles x 2 gate-col tiles x 16 K-slices (one K-half)
// each LDS weight read feeds 2 MFMAs (vs 1 before) -> W ds_read_b128 halved
__device__ __forceinline__ void gemm16(const char* pa, const __bf16* bw0, const __bf16* bw1,
                                       f32x4& c00, f32x4& c01, f32x4& c10, f32x4& c11) {
#pragma unroll
    for (int i = 0; i < 16; i++) {
        bf16x8 a0v = *(const bf16x8*)(pa + i * 1024);
        bf16x8 a1v = *(const bf16x8*)(pa + 32768 + i * 1024);
        bf16x8 w0  = *(const bf16x8*)(bw0 + i * 32);
        bf16x8 w1  = *(const bf16x8*)(bw1 + i * 32);
        c00 = MFMA(a0v, w0, c00); c01 = MFMA(a0v, w1, c01);
        c10 = MFMA(a1v, w0, c10); c11 = MFMA(a1v, w1, c11);
    }
}
__device__ __forceinline__ void gemm16s(const bf16x8* f0, const bf16x8* f1,
                                        const __bf16* bw0, const __bf16* bw1,
                                        f32x4& c00, f32x4& c01, f32x4& c10, f32x4& c11) {
#pragma unroll
    for (int i = 0; i < 16; i++) {
        bf16x8 w0 = *(const bf16x8*)(bw0 + i * 32);
        bf16x8 w1 = *(const bf16x8*)(bw1 + i * 32);
        c00 = MFMA(f0[i], w0, c00); c01 = MFMA(f0[i], w1, c01);
        c10 = MFMA(f1[i], w0, c10); c11 = MFMA(f1[i], w1, c11);
    }
}

// Pre-pass: xseqfrag[t] = emb[x[:,t]] in MFMA A-fragment order
__global__ void gather_emb(const int* __restrict__ x, const float* __restrict__ emb,
                           __bf16* __restrict__ xseqfrag) {
    int t = blockIdx.x;
    for (int u = threadIdx.x; u < 8192; u += 256) {
        int lane = u & 63, c = (u >> 6) & 31, bt = u >> 11;
        int row = lane & 15, quad = lane >> 4;
        int b = bt * 16 + row, k = c * 32 + quad * 8;
        int tok = x[b * TDIM + t];
        bf16x8 r = cvt8(emb + (size_t)tok * HDIM + k);
        *(bf16x8*)(xseqfrag + (size_t)t * FRAGE + (size_t)u * 8) = r;
    }
}

template <int BIG>
__global__ void __launch_bounds__(512, 1) rnn_all(
    const int* __restrict__ x, const float* __restrict__ tv,
    const float* __restrict__ emb,
    const float* __restrict__ w_ih1, const float* __restrict__ w_hh1,
    const float* __restrict__ b_ih1, const float* __restrict__ b_hh1,
    const float* __restrict__ gamma1, const float* __restrict__ beta1,
    const float* __restrict__ w_ih2, const float* __restrict__ w_hh2,
    const float* __restrict__ b_ih2, const float* __restrict__ b_hh2,
    const float* __restrict__ gamma2, const float* __restrict__ beta2,
    const float* __restrict__ fc_w, const float* __restrict__ fc_b,
    const float* __restrict__ mask1, const float* __restrict__ mask2,
    const __bf16* __restrict__ xseq, int use_xseq,
    int* __restrict__ l1h, int* __restrict__ l1o, int* __restrict__ l2h,
    int* __restrict__ poolg, const char* __restrict__ hzero,
    char* __restrict__ h1p, char* __restrict__ h2p, char* __restrict__ o1p,
    float* __restrict__ pooled, float* __restrict__ out) {
    __shared__ __bf16 wih_s[32 * WPAD];
    __shared__ __bf16 whh_s[32 * WPAD];
    __shared__ float bias_s[32];
    __shared__ float gbufX[32 * 68];     // col-major [gatecol][batch], x-GEMM partials
    __shared__ float gbufH[32 * 68];     // h-GEMM partials
    __shared__ float xh[8 * 68];
    __shared__ float stat_m[8], stat_r[8];
    __shared__ __align__(16) __bf16 hstage[512];
    __shared__ __align__(16) __bf16 ostage[512];

    const int tid   = threadIdx.x;
    const int layer = blockIdx.x & 1;
    const int lb    = blockIdx.x >> 1;      // 0..127 within layer group
    const int grp   = lb >> 4;              // 0..7 arrival sub-group
    const int fbase = lb * 8;

    const float* w_ih = layer ? w_ih2 : w_ih1;
    const float* w_hh = layer ? w_hh2 : w_hh1;
    const float* b_ih = layer ? b_ih2 : b_ih1;
    const float* b_hh = layer ? b_hh2 : b_hh1;
    const float* gam_ = layer ? gamma2 : gamma1;
    const float* bet_ = layer ? beta2  : beta1;
    const float* msk_ = layer ? mask2  : mask1;

    for (int idx = tid; idx < 32 * HDIM; idx += 512) {
        int n = idx >> 10, k = idx & 1023;
        int row = (n >> 3) * HDIM + fbase + (n & 7);
        wih_s[n * WPAD + k] = (__bf16)w_ih[row * HDIM + k];
        whh_s[n * WPAD + k] = (__bf16)w_hh[row * HDIM + k];
    }
    if (tid < 32) {
        int row = (tid >> 3) * HDIM + fbase + (tid & 7);
        bias_s[tid] = b_ih[row] + b_hh[row];
    }
    __syncthreads();
    if (BIG) // drop any pre-kernel (poison/memset) lines from this XCD's caches
        __builtin_amdgcn_fence(__ATOMIC_ACQUIRE, "agent");

    // wave roles: (batch-half bh, K-half kh, gemm g).  g=0 waves feed on x-input
    // (xseq / o1), g=1 waves feed on recurrent h -- only h-waves spin.
    const int lane = tid & 63;
    const int wv   = tid >> 6;              // 0..7
    const int bh   = wv & 1;
    const int kh   = (wv >> 1) & 1;
    const int g    = wv >> 2;               // 0 = x-GEMM wave, 1 = h-GEMM wave
    const int qm   = lane & 15;
    const int quad = lane >> 4;
    const int aoff = (bh * 64 + kh * 16) * 1024 + lane * 16;   // A chunk byte offset (bt=0)

    const __bf16* bw0 = (g ? whh_s : wih_s) + qm * WPAD + kh * 512 + quad * 8;
    const __bf16* bw1 = bw0 + 16 * WPAD;

    const int bb = tid >> 3, jj = tid & 7;
    const int feat = fbase + jj;
    const float gv = gam_[feat], bev = bet_[feat], mv = msk_[bb * HDIM + feat];
    float cst = 0.0f, pmax = -1e30f;

    const int soff = (((lane >> 4) * 32 + (lb >> 2)) * 64 + ((lb & 3) * 16 + (lane & 15))) * 16;

    char* h_self = layer ? h2p : h1p;
    int*  ch     = layer ? l2h : l1h;

#pragma unroll 1
    for (int t = 0; t < TDIM; t++) {
        f32x4 a00 = {0.f,0.f,0.f,0.f}, a01 = {0.f,0.f,0.f,0.f};
        f32x4 a10 = {0.f,0.f,0.f,0.f}, a11 = {0.f,0.f,0.f,0.f};

        if (g == 0) {
            if (layer == 0) {
                if (use_xseq) {
                    gemm16((const char*)xseq + (size_t)t * FRAGB + aoff, bw0, bw1,
                           a00, a01, a10, a11);
                } else {
                    const float* pe0 = emb + (size_t)x[(bh*32 + qm)*TDIM + t]*HDIM + kh*512 + quad*8;
                    const float* pe1 = emb + (size_t)x[(bh*32 + 16 + qm)*TDIM + t]*HDIM + kh*512 + quad*8;
#pragma unroll 4
                    for (int i = 0; i < 16; i++) {
                        bf16x8 v0 = cvt8(pe0 + i * 32), v1 = cvt8(pe1 + i * 32);
                        bf16x8 w0 = *(const bf16x8*)(bw0 + i * 32);
                        bf16x8 w1 = *(const bf16x8*)(bw1 + i * 32);
                        a00 = MFMA(v0, w0, a00); a01 = MFMA(v0, w1, a01);
                        a10 = MFMA(v1, w0, a10); a11 = MFMA(v1, w1, a11);
                    }
                }
            } else {
                wspin(l1o + (size_t)t * NGRP * 16);
                if (BIG) {
                    gemm16(o1p + (size_t)t * FRAGB + aoff, bw0, bw1, a00, a01, a10, a11);
                } else {
                    bf16x8 f0[16], f1[16];
                    const char* p = o1p + (size_t)(t & (SLOTS - 1)) * FRAGB + aoff;
                    GLF16(f0, p); GLF16(f1, p + 32768); WAITV();
                    gemm16s(f0, f1, bw0, bw1, a00, a01, a10, a11);
                }
            }
        } else {
            if (t >= 1) wspin(ch + (size_t)(t - 1) * NGRP * 16);
            if (BIG) {
                const char* src = (t == 0) ? hzero : (const char*)(h_self + (size_t)(t - 1) * FRAGB);
                gemm16(src + aoff, bw0, bw1, a00, a01, a10, a11);
            } else {
                bf16x8 f0[16], f1[16];
                const char* p = h_self + (size_t)(t & 1) * FRAGB + aoff;
                GLF16(f0, p); GLF16(f1, p + 32768); WAITV();
                gemm16s(f0, f1, bw0, bw1, a00, a01, a10, a11);
            }
        }

        // ---- combine: col-major b128, 2 phases (kh0 write, kh1 add); X/H separate ----
        float* myg = g ? gbufH : gbufX;
        const int r0  = bh * 32 + quad * 4;
        const int i00 = qm * 68 + r0, i01 = (16 + qm) * 68 + r0;
        if (kh == 0) {
            if (!g) {
                float b0 = bias_s[qm], b1 = bias_s[16 + qm];
                f32x4 s0 = {b0, b0, b0, b0}, s1 = {b1, b1, b1, b1};
                a00 += s0; a01 += s1; a10 += s0; a11 += s1;
            }
            *(f32x4*)&myg[i00]      = a00;
            *(f32x4*)&myg[i01]      = a01;
            *(f32x4*)&myg[i00 + 16] = a10;
            *(f32x4*)&myg[i01 + 16] = a11;
        }
        __syncthreads();
        if (kh == 1) {
            f32x4 v;
            v = *(const f32x4*)&myg[i00];      v += a00; *(f32x4*)&myg[i00]      = v;
            v = *(const f32x4*)&myg[i01];      v += a01; *(f32x4*)&myg[i01]      = v;
            v = *(const f32x4*)&myg[i00 + 16]; v += a10; *(f32x4*)&myg[i00 + 16] = v;
            v = *(const f32x4*)&myg[i01 + 16]; v += a11; *(f32x4*)&myg[i01 + 16] = v;
        }
        __syncthreads();

        // ---- LSTM cell ----
        const int cb = jj * 68 + bb;
        float gi = gbufX[cb]          + gbufH[cb];
        float gf = gbufX[cb + 8*68]   + gbufH[cb + 8*68];
        float gg = gbufX[cb + 16*68]  + gbufH[cb + 16*68];
        float go = gbufX[cb + 24*68]  + gbufH[cb + 24*68];
        cst = sigf(gf) * cst + sigf(gi) * tanhf(gg);
        float h = sigf(go) * tanhf(cst);
        hstage[tid] = (__bf16)h;
        xh[jj * 68 + bb] = h;
        __syncthreads();

        // ---- EARLY h store + arrive (wave0) -- recurrence no longer waits on BN ----
        size_t hslot = BIG ? (size_t)t * FRAGB : (size_t)((t + 1) & 1) * FRAGB;
        if (wv == 0) {
            i32x4 val = *(const i32x4*)(hstage + lane * 8);
            GS16(h_self + hslot + soff, val);
        }
        // BN stats (all waves) overlap wave0's store latency
        float v = xh[wv * 68 + lane];
        float s1 = v, s2 = v * v;
#pragma unroll
        for (int off = 32; off; off >>= 1) {
            s1 += __shfl_xor(s1, off);
            s2 += __shfl_xor(s2, off);
        }
        if (lane == 0) {
            float m  = s1 * (1.0f / 64.0f);
            float va = s2 * (1.0f / 64.0f) - m * m;
            stat_m[wv] = m;
            stat_r[wv] = rsqrtf(va + 1e-5f);
        }
        if (wv == 0) {
            WAITV();                 // wave0's sc0sc1 stores reached MALL
            if (lane == 0)
                __hip_atomic_fetch_add(ch + ((size_t)t * NGRP + grp) * 16, 1,
                                       __ATOMIC_RELAXED, __HIP_MEMORY_SCOPE_AGENT);
        }
        __syncthreads();

        float o = ((h - stat_m[jj]) * stat_r[jj] * gv + bev) * mv;
        if (layer == 0) {
            ostage[tid] = (__bf16)o;
            __syncthreads();
            if (wv == 1) {
                if (!BIG && t >= SLOTS)   // o1 ring-slot reuse guard, off the h-path
                    wspin(l2h + (size_t)(t - SLOTS) * NGRP * 16);
                i32x4 val = *(const i32x4*)(ostage + lane * 8);
                size_t oslot = BIG ? (size_t)t * FRAGB : (size_t)(t & (SLOTS - 1)) * FRAGB;
                GS16(o1p + oslot + soff, val);
                WAITV();
                if (lane == 0)
                    __hip_atomic_fetch_add(l1o + ((size_t)t * NGRP + grp) * 16, 1,
                                           __ATOMIC_RELAXED, __HIP_MEMORY_SCOPE_AGENT);
            }
        } else {
            pmax = fmaxf(pmax, o);
        }
    }

    if (layer == 1) {
        __hip_atomic_store(&pooled[bb * HDIM + feat], pmax,
                           __ATOMIC_RELAXED, __HIP_MEMORY_SCOPE_AGENT);
        WAITV();
        __syncthreads();
        if (tid == 0)
            __hip_atomic_fetch_add(poolg, 1, __ATOMIC_RELAXED, __HIP_MEMORY_SCOPE_AGENT);

        if (lb == 0) {
            // ============== FC + BCE loss (one block) ==============
            spin1(poolg, 128);
            __builtin_amdgcn_fence(__ATOMIC_ACQUIRE, "agent");
            int b  = wv * 8 + (lane >> 3);
            int l8 = lane & 7;
            float s = 0.0f;
            for (int f = l8 * 128; f < l8 * 128 + 128; f++)
                s += pooled[b * HDIM + f] * fc_w[f];
            s += __shfl_xor(s, 1); s += __shfl_xor(s, 2); s += __shfl_xor(s, 4);
            float logit = s + fc_b[0];
            if (l8 == 0) {
                out[1 + b] = logit;
                gbufX[b] = fmaxf(logit, 0.0f) - logit * tv[b] + log1pf(expf(-fabsf(logit)));
            }
            __syncthreads();
            if (tid < 64) {
                float term = gbufX[tid];
#pragma unroll
                for (int off = 32; off; off >>= 1) term += __shfl_xor(term, off);
                if (tid == 0) out[0] = term * (1.0f / 64.0f);
            }
        }
    }
}

extern "C" void kernel_launch(void* const* d_in, const int* in_sizes, int n_in,
                              void* d_out, int out_size, void* d_ws, size_t ws_size,
                              hipStream_t stream) {
    const int*   x    = (const int*)d_in[0];
    const float* tv   = (const float*)d_in[1];
    const float* emb  = (const float*)d_in[2];
    const float* wih1 = (const float*)d_in[3];
    const float* whh1 = (const float*)d_in[4];
    const float* bih1 = (const float*)d_in[5];
    const float* bhh1 = (const float*)d_in[6];
    const float* g1   = (const float*)d_in[7];
    const float* be1  = (const float*)d_in[8];
    const float* wih2 = (const float*)d_in[9];
    const float* whh2 = (const float*)d_in[10];
    const float* bih2 = (const float*)d_in[11];
    const float* bhh2 = (const float*)d_in[12];
    const float* g2   = (const float*)d_in[13];
    const float* be2  = (const float*)d_in[14];
    const float* fcw  = (const float*)d_in[15];
    const float* fcb  = (const float*)d_in[16];
    const float* m1   = (const float*)d_in[17];
    const float* m2   = (const float*)d_in[18];

    char* w = (char*)d_ws;
    float* out = (float*)d_out;

    // ---- big (t-indexed, L2/MALL-cached broadcast) layout ----
    const size_t SEQB = (size_t)TDIM * FRAGB;                  // 64 MB
    size_t boff = 0;
    int*   B_l1h   = (int*)(w + boff); boff += 262144;
    int*   B_l1o   = (int*)(w + boff); boff += 262144;
    int*   B_l2h   = (int*)(w + boff); boff += 262144;
    int*   B_poolg = (int*)(w + boff); boff += 4096;
    char*  B_hzero = w + boff;         boff += FRAGB;          // memset prefix ends here
    size_t B_msz   = boff;
    char*  B_h1    = w + boff;         boff += SEQB;
    char*  B_h2    = w + boff;         boff += SEQB;
    char*  B_o1    = w + boff;         boff += SEQB;
    float* B_pool  = (float*)(w + boff); boff += 262144;
    __bf16* B_xseq = (__bf16*)(w + boff); boff += SEQB;
    size_t need_big = boff;

    if (ws_size >= need_big) {
        hipMemsetAsync(d_ws, 0, B_msz, stream);
        gather_emb<<<dim3(TDIM), dim3(256), 0, stream>>>(x, emb, B_xseq);
        int use_xseq = 1;
        void* args[] = {&x, &tv, &emb, &wih1, &whh1, &bih1, &bhh1, &g1, &be1,
                        &wih2, &whh2, &bih2, &bhh2, &g2, &be2, &fcw, &fcb, &m1, &m2,
                        (void*)&B_xseq, &use_xseq,
                        &B_l1h, &B_l1o, &B_l2h, &B_poolg, (void*)&B_hzero,
                        &B_h1, &B_h2, &B_o1, &B_pool, &out};
        hipLaunchCooperativeKernel((void*)rnn_all<1>, dim3(256), dim3(512), args, 0, stream);
        return;
    }

    // ---- small fallback (sc0sc1 ring buffers) ----
    int*    l1h    = (int*)(w);
    int*    l1o    = (int*)(w + 262144);
    int*    l2h    = (int*)(w + 524288);
    int*    poolg  = (int*)(w + 786432);
    char*   hzero  = w;                            // unused in small mode
    char*   h1frag = w + 790528;                   // 256 KB (2 slots)
    char*   h2frag = h1frag + 262144;              // 256 KB (2 slots)
    char*   o1frag = h2frag + 262144;              // 512 KB (4 slots)
    float*  pooled = (float*)(o1frag + 524288);
    __bf16* xseq   = (__bf16*)((char*)pooled + 262144);
    size_t fixed   = (size_t)((char*)xseq - w);
    int use_xseq = (ws_size >= fixed + SEQB) ? 1 : 0;

    hipMemsetAsync(d_ws, 0, fixed, stream);
    if (use_xseq)
        gather_emb<<<dim3(TDIM), dim3(256), 0, stream>>>(x, emb, xseq);

    void* args[] = {&x, &tv, &emb, &wih1, &whh1, &bih1, &bhh1, &g1, &be1,
                    &wih2, &whh2, &bih2, &bhh2, &g2, &be2, &fcw, &fcb, &m1, &m2,
                    (void*)&xseq, &use_xseq,
                    &l1h, &l1o, &l2h, &poolg, (void*)&hzero,
                    &h1frag, &h2frag, &o1frag, &pooled, &out};
    hipLaunchCooperativeKernel((void*)rnn_all<0>, dim3(256), dim3(512), args, 0, stream);
}

// Round 3
// 3766.755 us; speedup vs baseline: 1.0796x; 1.0376x over previous
//
#include <hip/hip_runtime.h>

#define HDIM  1024
#define BDIM  64
#define TDIM  512
#define FRAGB 131072            // bytes per fragment-order activation matrix (64x1024 bf16)
#define FRAGE 65536             // elements per fragment matrix
#define SLOTS 4                 // o1 ring slots (small mode only)
#define NGRP  8                 // arrival sub-groups per layer (16 blocks each)

typedef __bf16 bf16x8 __attribute__((ext_vector_type(8)));
typedef float  f32x4  __attribute__((ext_vector_type(4)));
typedef int    i32x4  __attribute__((ext_vector_type(4)));

#define MFMA(a, b, c) __builtin_amdgcn_mfma_f32_16x16x32_bf16(a, b, c, 0, 0, 0)

// MALL-coherent 16B load (bypasses L1+L2) -- small mode only
#define GL(dst, p, off) \
    asm volatile("global_load_dwordx4 %0, %1, off offset:" off " sc0 sc1" \
                 : "=v"(dst) : "v"(p) : "memory")
#define GLF16(f, p) do { \
    const char* p0_ = (const char*)(p); \
    const char* p1_ = p0_ + 4096; const char* p2_ = p0_ + 8192; const char* p3_ = p0_ + 12288; \
    GL(f[0],  p0_, "0"); GL(f[1],  p0_, "1024"); GL(f[2],  p0_, "2048"); GL(f[3],  p0_, "3072"); \
    GL(f[4],  p1_, "0"); GL(f[5],  p1_, "1024"); GL(f[6],  p1_, "2048"); GL(f[7],  p1_, "3072"); \
    GL(f[8],  p2_, "0"); GL(f[9],  p2_, "1024"); GL(f[10], p2_, "2048"); GL(f[11], p2_, "3072"); \
    GL(f[12], p3_, "0"); GL(f[13], p3_, "1024"); GL(f[14], p3_, "2048"); GL(f[15], p3_, "3072"); \
} while (0)
#define WAITV() asm volatile("s_waitcnt vmcnt(0)" ::: "memory")
#define GS16(p, v) \
    asm volatile("global_store_dwordx4 %0, %1, off sc0 sc1" :: "v"(p), "v"(v) : "memory")

// HW-native activations: v_exp_f32 (2^x) + v_rcp_f32, ~1e-7 abs err (<< bf16 quantization)
__device__ __forceinline__ float sigf(float x) {
    return __builtin_amdgcn_rcpf(1.0f + __builtin_amdgcn_exp2f(-1.44269504f * x));
}
__device__ __forceinline__ float tanh_fast(float x) {
    return 2.0f * __builtin_amdgcn_rcpf(1.0f + __builtin_amdgcn_exp2f(-2.88539008f * x)) - 1.0f;
}

__device__ __forceinline__ bf16x8 cvt8(const float* p) {
    const f32x4* q = (const f32x4*)p;
    f32x4 a = q[0], b = q[1];
    bf16x8 r;
    r[0] = (__bf16)a[0]; r[1] = (__bf16)a[1]; r[2] = (__bf16)a[2]; r[3] = (__bf16)a[3];
    r[4] = (__bf16)b[0]; r[5] = (__bf16)b[1]; r[6] = (__bf16)b[2]; r[7] = (__bf16)b[3];
    return r;
}

// ---- wave-local spin on 8 sub-counters (16-way fan-in each); no block barrier ----
__device__ __forceinline__ void wspin(const int* base) {
    int l = threadIdx.x & 63;
    const int* p = (l < 8) ? base + l * 16 : nullptr;
    for (;;) {
        int v = p ? __hip_atomic_load(p, __ATOMIC_RELAXED, __HIP_MEMORY_SCOPE_AGENT) : 16;
        if (__all(v >= 16)) break;
        __builtin_amdgcn_s_sleep(1);
    }
}
__device__ __forceinline__ void spin1(const int* c, int n) {
    if (threadIdx.x == 0)
        while (__hip_atomic_load(c, __ATOMIC_RELAXED, __HIP_MEMORY_SCOPE_AGENT) < n)
            __builtin_amdgcn_s_sleep(1);
    __syncthreads();
}

// streaming GEMM slice, weights in REGISTERS (no LDS in the loop):
// 2 batch tiles x 2 gate-col tiles x 16 K-slices; A from cached global
__device__ __forceinline__ void gemm16r(const char* pa,
                                        const bf16x8 (&w0)[16], const bf16x8 (&w1)[16],
                                        f32x4& c00, f32x4& c01, f32x4& c10, f32x4& c11) {
#pragma unroll
    for (int i = 0; i < 16; i++) {
        bf16x8 a0v = *(const bf16x8*)(pa + i * 1024);
        bf16x8 a1v = *(const bf16x8*)(pa + 32768 + i * 1024);
        c00 = MFMA(a0v, w0[i], c00); c01 = MFMA(a0v, w1[i], c01);
        c10 = MFMA(a1v, w0[i], c10); c11 = MFMA(a1v, w1[i], c11);
    }
}

// Pre-pass: xseqfrag[t] = emb[x[:,t]] in MFMA A-fragment order
__global__ void gather_emb(const int* __restrict__ x, const float* __restrict__ emb,
                           __bf16* __restrict__ xseqfrag) {
    int t = blockIdx.x;
    for (int u = threadIdx.x; u < 8192; u += 256) {
        int lane = u & 63, c = (u >> 6) & 31, bt = u >> 11;
        int row = lane & 15, quad = lane >> 4;
        int b = bt * 16 + row, k = c * 32 + quad * 8;
        int tok = x[b * TDIM + t];
        bf16x8 r = cvt8(emb + (size_t)tok * HDIM + k);
        *(bf16x8*)(xseqfrag + (size_t)t * FRAGE + (size_t)u * 8) = r;
    }
}

template <int BIG>
__global__ void __launch_bounds__(512, 2) rnn_all(
    const int* __restrict__ x, const float* __restrict__ tv,
    const float* __restrict__ emb,
    const float* __restrict__ w_ih1, const float* __restrict__ w_hh1,
    const float* __restrict__ b_ih1, const float* __restrict__ b_hh1,
    const float* __restrict__ gamma1, const float* __restrict__ beta1,
    const float* __restrict__ w_ih2, const float* __restrict__ w_hh2,
    const float* __restrict__ b_ih2, const float* __restrict__ b_hh2,
    const float* __restrict__ gamma2, const float* __restrict__ beta2,
    const float* __restrict__ fc_w, const float* __restrict__ fc_b,
    const float* __restrict__ mask1, const float* __restrict__ mask2,
    const __bf16* __restrict__ xseq, int use_xseq,
    int* __restrict__ l1h, int* __restrict__ l1o, int* __restrict__ l2h,
    int* __restrict__ poolg, const char* __restrict__ hzero,
    char* __restrict__ h1p, char* __restrict__ h2p, char* __restrict__ o1p,
    float* __restrict__ pooled, float* __restrict__ out) {
    __shared__ float bias_s[32];
    __shared__ float gbufX0[32 * 68];    // col-major [gatecol][batch] partials
    __shared__ float gbufX1[32 * 68];
    __shared__ float gbufH0[32 * 68];
    __shared__ float gbufH1[32 * 68];
    __shared__ float xh[8 * 68];
    __shared__ float stat_m[8], stat_r[8];
    __shared__ __align__(16) __bf16 hstage[512];
    __shared__ __align__(16) __bf16 ostage[512];

    const int tid   = threadIdx.x;
    const int layer = blockIdx.x & 1;
    const int lb    = blockIdx.x >> 1;      // 0..127 within layer group
    const int grp   = lb >> 4;              // 0..7 arrival sub-group
    const int fbase = lb * 8;

    const float* w_ih = layer ? w_ih2 : w_ih1;
    const float* w_hh = layer ? w_hh2 : w_hh1;
    const float* b_ih = layer ? b_ih2 : b_ih1;
    const float* b_hh = layer ? b_hh2 : b_hh1;
    const float* gam_ = layer ? gamma2 : gamma1;
    const float* bet_ = layer ? beta2  : beta1;
    const float* msk_ = layer ? mask2  : mask1;

    if (tid < 32) {
        int row = (tid >> 3) * HDIM + fbase + (tid & 7);
        bias_s[tid] = b_ih[row] + b_hh[row];
    }
    __syncthreads();
    if (BIG) // drop any pre-kernel (poison/memset) lines from this XCD's caches
        __builtin_amdgcn_fence(__ATOMIC_ACQUIRE, "agent");

    // wave roles: (batch-half bh, K-half kh, gemm g). g=0 waves feed on x-input
    // (xseq / o1), g=1 waves feed on recurrent h -- only h-waves spin.
    const int lane = tid & 63;
    const int wv   = tid >> 6;              // 0..7
    const int bh   = wv & 1;
    const int kh   = (wv >> 1) & 1;
    const int g    = wv >> 2;               // 0 = x-GEMM wave, 1 = h-GEMM wave
    const int qm   = lane & 15;
    const int quad = lane >> 4;
    const int aoff = (bh * 64 + kh * 16) * 1024 + lane * 16;   // A chunk byte offset

    // ---- weight B-fragments into registers: 2 gate-cols x 16 K-slices = 128 VGPR ----
    bf16x8 wr0[16], wr1[16];
    {
        const float* wsrc = g ? w_hh : w_ih;
        const float* p0 = wsrc + (size_t)((qm >> 3) * HDIM + fbase + (qm & 7)) * HDIM
                               + kh * 512 + quad * 8;
        const float* p1 = wsrc + (size_t)(((16 + qm) >> 3) * HDIM + fbase + (qm & 7)) * HDIM
                               + kh * 512 + quad * 8;
#pragma unroll
        for (int i = 0; i < 16; i++) {
            wr0[i] = cvt8(p0 + i * 32);
            wr1[i] = cvt8(p1 + i * 32);
        }
    }

    const int bb = tid >> 3, jj = tid & 7;
    const int feat = fbase + jj;
    const float gv = gam_[feat], bev = bet_[feat], mv = msk_[bb * HDIM + feat];
    float cst = 0.0f, pmax = -1e30f;

    const int soff = (((lane >> 4) * 32 + (lb >> 2)) * 64 + ((lb & 3) * 16 + (lane & 15))) * 16;

    char* h_self = layer ? h2p : h1p;
    int*  ch     = layer ? l2h : l1h;

#pragma unroll 1
    for (int t = 0; t < TDIM; t++) {
        f32x4 a00 = {0.f,0.f,0.f,0.f}, a01 = {0.f,0.f,0.f,0.f};
        f32x4 a10 = {0.f,0.f,0.f,0.f}, a11 = {0.f,0.f,0.f,0.f};

        if (g == 0) {
            if (layer == 0) {
                if (use_xseq) {
                    gemm16r((const char*)xseq + (size_t)t * FRAGB + aoff, wr0, wr1,
                            a00, a01, a10, a11);
                } else {
                    const float* pe0 = emb + (size_t)x[(bh*32 + qm)*TDIM + t]*HDIM + kh*512 + quad*8;
                    const float* pe1 = emb + (size_t)x[(bh*32 + 16 + qm)*TDIM + t]*HDIM + kh*512 + quad*8;
#pragma unroll 4
                    for (int i = 0; i < 16; i++) {
                        bf16x8 v0 = cvt8(pe0 + i * 32), v1 = cvt8(pe1 + i * 32);
                        a00 = MFMA(v0, wr0[i], a00); a01 = MFMA(v0, wr1[i], a01);
                        a10 = MFMA(v1, wr0[i], a10); a11 = MFMA(v1, wr1[i], a11);
                    }
                }
            } else {
                wspin(l1o + (size_t)t * NGRP * 16);
                if (BIG) {
                    gemm16r(o1p + (size_t)t * FRAGB + aoff, wr0, wr1, a00, a01, a10, a11);
                } else {
                    const char* p = o1p + (size_t)(t & (SLOTS - 1)) * FRAGB + aoff;
                    bf16x8 f[16];
                    GLF16(f, p); WAITV();
#pragma unroll
                    for (int i = 0; i < 16; i++) {
                        a00 = MFMA(f[i], wr0[i], a00); a01 = MFMA(f[i], wr1[i], a01);
                    }
                    GLF16(f, p + 32768); WAITV();
#pragma unroll
                    for (int i = 0; i < 16; i++) {
                        a10 = MFMA(f[i], wr0[i], a10); a11 = MFMA(f[i], wr1[i], a11);
                    }
                }
            }
        } else {
            if (t >= 1) wspin(ch + (size_t)(t - 1) * NGRP * 16);
            if (BIG) {
                const char* src = (t == 0) ? hzero : (const char*)(h_self + (size_t)(t - 1) * FRAGB);
                gemm16r(src + aoff, wr0, wr1, a00, a01, a10, a11);
            } else {
                const char* p = h_self + (size_t)(t & 1) * FRAGB + aoff;
                bf16x8 f[16];
                GLF16(f, p); WAITV();
#pragma unroll
                for (int i = 0; i < 16; i++) {
                    a00 = MFMA(f[i], wr0[i], a00); a01 = MFMA(f[i], wr1[i], a01);
                }
                GLF16(f, p + 32768); WAITV();
#pragma unroll
                for (int i = 0; i < 16; i++) {
                    a10 = MFMA(f[i], wr0[i], a10); a11 = MFMA(f[i], wr1[i], a11);
                }
            }
        }

        // ---- combine: 4 private partial buffers, ONE barrier (no ordering stall) ----
        float* myg = g ? (kh ? gbufH1 : gbufH0) : (kh ? gbufX1 : gbufX0);
        const int r0  = bh * 32 + quad * 4;
        const int i00 = qm * 68 + r0, i01 = (16 + qm) * 68 + r0;
        if (!g && !kh) {
            float b0 = bias_s[qm], b1 = bias_s[16 + qm];
            f32x4 s0 = {b0, b0, b0, b0}, s1 = {b1, b1, b1, b1};
            a00 += s0; a01 += s1; a10 += s0; a11 += s1;
        }
        *(f32x4*)&myg[i00]      = a00;
        *(f32x4*)&myg[i01]      = a01;
        *(f32x4*)&myg[i00 + 16] = a10;
        *(f32x4*)&myg[i01 + 16] = a11;
        __syncthreads();

        // ---- LSTM cell ----
        const int cb = jj * 68 + bb;
        float gi = gbufX0[cb] + gbufX1[cb] + gbufH0[cb] + gbufH1[cb];
        float gf = gbufX0[cb + 8*68] + gbufX1[cb + 8*68] + gbufH0[cb + 8*68] + gbufH1[cb + 8*68];
        float gg = gbufX0[cb + 16*68] + gbufX1[cb + 16*68] + gbufH0[cb + 16*68] + gbufH1[cb + 16*68];
        float go = gbufX0[cb + 24*68] + gbufX1[cb + 24*68] + gbufH0[cb + 24*68] + gbufH1[cb + 24*68];
        cst = sigf(gf) * cst + sigf(gi) * tanh_fast(gg);
        float h = sigf(go) * tanh_fast(cst);
        hstage[tid] = (__bf16)h;
        xh[jj * 68 + bb] = h;
        __syncthreads();

        // ---- EARLY h store + arrive (wave0) -- recurrence no longer waits on BN ----
        size_t hslot = BIG ? (size_t)t * FRAGB : (size_t)((t + 1) & 1) * FRAGB;
        if (wv == 0) {
            i32x4 val = *(const i32x4*)(hstage + lane * 8);
            GS16(h_self + hslot + soff, val);
        }
        // BN stats (all waves) overlap wave0's store latency
        float v = xh[wv * 68 + lane];
        float s1 = v, s2 = v * v;
#pragma unroll
        for (int off = 32; off; off >>= 1) {
            s1 += __shfl_xor(s1, off);
            s2 += __shfl_xor(s2, off);
        }
        if (lane == 0) {
            float m  = s1 * (1.0f / 64.0f);
            float va = s2 * (1.0f / 64.0f) - m * m;
            stat_m[wv] = m;
            stat_r[wv] = rsqrtf(va + 1e-5f);
        }
        if (wv == 0) {
            WAITV();                 // wave0's sc0sc1 stores reached MALL
            if (lane == 0)
                __hip_atomic_fetch_add(ch + ((size_t)t * NGRP + grp) * 16, 1,
                                       __ATOMIC_RELAXED, __HIP_MEMORY_SCOPE_AGENT);
        }
        __syncthreads();

        float o = ((h - stat_m[jj]) * stat_r[jj] * gv + bev) * mv;
        if (layer == 0) {
            ostage[tid] = (__bf16)o;
            __syncthreads();
            if (wv == 1) {
                if (!BIG && t >= SLOTS)   // o1 ring-slot reuse guard, off the h-path
                    wspin(l2h + (size_t)(t - SLOTS) * NGRP * 16);
                i32x4 val = *(const i32x4*)(ostage + lane * 8);
                size_t oslot = BIG ? (size_t)t * FRAGB : (size_t)(t & (SLOTS - 1)) * FRAGB;
                GS16(o1p + oslot + soff, val);
                WAITV();
                if (lane == 0)
                    __hip_atomic_fetch_add(l1o + ((size_t)t * NGRP + grp) * 16, 1,
                                           __ATOMIC_RELAXED, __HIP_MEMORY_SCOPE_AGENT);
            }
        } else {
            pmax = fmaxf(pmax, o);
        }
    }

    if (layer == 1) {
        __hip_atomic_store(&pooled[bb * HDIM + feat], pmax,
                           __ATOMIC_RELAXED, __HIP_MEMORY_SCOPE_AGENT);
        WAITV();
        __syncthreads();
        if (tid == 0)
            __hip_atomic_fetch_add(poolg, 1, __ATOMIC_RELAXED, __HIP_MEMORY_SCOPE_AGENT);

        if (lb == 0) {
            // ============== FC + BCE loss (one block) ==============
            spin1(poolg, 128);
            __builtin_amdgcn_fence(__ATOMIC_ACQUIRE, "agent");
            int b  = wv * 8 + (lane >> 3);
            int l8 = lane & 7;
            float s = 0.0f;
            for (int f = l8 * 128; f < l8 * 128 + 128; f++)
                s += pooled[b * HDIM + f] * fc_w[f];
            s += __shfl_xor(s, 1); s += __shfl_xor(s, 2); s += __shfl_xor(s, 4);
            float logit = s + fc_b[0];
            if (l8 == 0) {
                out[1 + b] = logit;
                gbufX0[b] = fmaxf(logit, 0.0f) - logit * tv[b] + log1pf(expf(-fabsf(logit)));
            }
            __syncthreads();
            if (tid < 64) {
                float term = gbufX0[tid];
#pragma unroll
                for (int off = 32; off; off >>= 1) term += __shfl_xor(term, off);
                if (tid == 0) out[0] = term * (1.0f / 64.0f);
            }
        }
    }
}

extern "C" void kernel_launch(void* const* d_in, const int* in_sizes, int n_in,
                              void* d_out, int out_size, void* d_ws, size_t ws_size,
                              hipStream_t stream) {
    const int*   x    = (const int*)d_in[0];
    const float* tv   = (const float*)d_in[1];
    const float* emb  = (const float*)d_in[2];
    const float* wih1 = (const float*)d_in[3];
    const float* whh1 = (const float*)d_in[4];
    const float* bih1 = (const float*)d_in[5];
    const float* bhh1 = (const float*)d_in[6];
    const float* g1   = (const float*)d_in[7];
    const float* be1  = (const float*)d_in[8];
    const float* wih2 = (const float*)d_in[9];
    const float* whh2 = (const float*)d_in[10];
    const float* bih2 = (const float*)d_in[11];
    const float* bhh2 = (const float*)d_in[12];
    const float* g2   = (const float*)d_in[13];
    const float* be2  = (const float*)d_in[14];
    const float* fcw  = (const float*)d_in[15];
    const float* fcb  = (const float*)d_in[16];
    const float* m1   = (const float*)d_in[17];
    const float* m2   = (const float*)d_in[18];

    char* w = (char*)d_ws;
    float* out = (float*)d_out;

    // ---- big (t-indexed, L2/MALL-cached broadcast) layout ----
    const size_t SEQB = (size_t)TDIM * FRAGB;                  // 64 MB
    size_t boff = 0;
    int*   B_l1h   = (int*)(w + boff); boff += 262144;
    int*   B_l1o   = (int*)(w + boff); boff += 262144;
    int*   B_l2h   = (int*)(w + boff); boff += 262144;
    int*   B_poolg = (int*)(w + boff); boff += 4096;
    char*  B_hzero = w + boff;         boff += FRAGB;          // memset prefix ends here
    size_t B_msz   = boff;
    char*  B_h1    = w + boff;         boff += SEQB;
    char*  B_h2    = w + boff;         boff += SEQB;
    char*  B_o1    = w + boff;         boff += SEQB;
    float* B_pool  = (float*)(w + boff); boff += 262144;
    __bf16* B_xseq = (__bf16*)(w + boff); boff += SEQB;
    size_t need_big = boff;

    if (ws_size >= need_big) {
        hipMemsetAsync(d_ws, 0, B_msz, stream);
        gather_emb<<<dim3(TDIM), dim3(256), 0, stream>>>(x, emb, B_xseq);
        int use_xseq = 1;
        void* args[] = {&x, &tv, &emb, &wih1, &whh1, &bih1, &bhh1, &g1, &be1,
                        &wih2, &whh2, &bih2, &bhh2, &g2, &be2, &fcw, &fcb, &m1, &m2,
                        (void*)&B_xseq, &use_xseq,
                        &B_l1h, &B_l1o, &B_l2h, &B_poolg, (void*)&B_hzero,
                        &B_h1, &B_h2, &B_o1, &B_pool, &out};
        hipLaunchCooperativeKernel((void*)rnn_all<1>, dim3(256), dim3(512), args, 0, stream);
        return;
    }

    // ---- small fallback (sc0sc1 ring buffers) ----
    int*    l1h    = (int*)(w);
    int*    l1o    = (int*)(w + 262144);
    int*    l2h    = (int*)(w + 524288);
    int*    poolg  = (int*)(w + 786432);
    char*   hzero  = w;                            // unused in small mode
    char*   h1frag = w + 790528;                   // 256 KB (2 slots)
    char*   h2frag = h1frag + 262144;              // 256 KB (2 slots)
    char*   o1frag = h2frag + 262144;              // 512 KB (4 slots)
    float*  pooled = (float*)(o1frag + 524288);
    __bf16* xseq   = (__bf16*)((char*)pooled + 262144);
    size_t fixed   = (size_t)((char*)xseq - w);
    int use_xseq = (ws_size >= fixed + SEQB) ? 1 : 0;

    hipMemsetAsync(d_ws, 0, fixed, stream);
    if (use_xseq)
        gather_emb<<<dim3(TDIM), dim3(256), 0, stream>>>(x, emb, xseq);

    void* args[] = {&x, &tv, &emb, &wih1, &whh1, &bih1, &bhh1, &g1, &be1,
                    &wih2, &whh2, &bih2, &bhh2, &g2, &be2, &fcw, &fcb, &m1, &m2,
                    (void*)&xseq, &use_xseq,
                    &l1h, &l1o, &l2h, &poolg, (void*)&hzero,
                    &h1frag, &h2frag, &o1frag, &pooled, &out};
    hipLaunchCooperativeKernel((void*)rnn_all<0>, dim3(256), dim3(512), args, 0, stream);
}